// Round 9
// baseline (116.373 us; speedup 1.0000x reference)
//
#include <hip/hip_runtime.h>
#include <stdint.h>

#define DD 128                 // drug feature dim
#define HH 32                  // hidden dim
#define TABQ (4096 * DD / 4)   // float4 count of drug table
#define BLOB_OFF (1u << 20)    // weight fragment blob offset inside d_ws (bytes)

typedef _Float16 f16;
typedef _Float16 f16x2 __attribute__((ext_vector_type(2)));
typedef _Float16 f16x4 __attribute__((ext_vector_type(4)));
typedef _Float16 f16x8 __attribute__((ext_vector_type(8)));
typedef float    f32x4 __attribute__((ext_vector_type(4)));
typedef uint32_t u32x4 __attribute__((ext_vector_type(4)));

#define GL1(p)  ((const __attribute__((address_space(1))) void*)(p))
#define LDS3(p) ((__attribute__((address_space(3))) void*)(p))

// Pre-pass: (a) drug table f32->f16 (blocks 0..511); (b) weight-fragment blob
// at ws+1MB (block 512): W1 slots 0..511, W2 512..639, W3 640..767,
// W4-column-fragment 768..831. Fragments are role-symmetric (A vs B operand),
// so the swapped-MFMA main kernel reuses them unchanged.
__global__ __launch_bounds__(256)
void synergy_prepass(const float* __restrict__ drug,
                     const float* __restrict__ W1, const float* __restrict__ W2,
                     const float* __restrict__ W3, const float* __restrict__ W4,
                     f16* __restrict__ tab)
{
    const int tid = threadIdx.x;
    if ((int)blockIdx.x == 512) {
        f16x8* __restrict__ blob16 = (f16x8*)((char*)tab + BLOB_OFF);
        const float4* __restrict__ W1v = (const float4*)W1;
        #pragma unroll
        for (int p = 0; p < 2; ++p) {
            const int S = p * 256 + tid;
            const int t = S >> 8, f = (S >> 6) & 3, l = S & 63;
            const int mm = l & 15, qq = l >> 4;
            const int c4 = (t * 16 + mm) * (DD / 4) + f * 8 + qq * 2;
            const float4 w0 = W1v[c4], w1 = W1v[c4 + 1];
            f16x8 r;
            r[0]=(f16)w0.x; r[1]=(f16)w0.y; r[2]=(f16)w0.z; r[3]=(f16)w0.w;
            r[4]=(f16)w1.x; r[5]=(f16)w1.y; r[6]=(f16)w1.z; r[7]=(f16)w1.w;
            blob16[S] = r;
        }
        {
            const int B = tid & 127;
            const int t = B >> 6, l = B & 63;
            const int mm = l & 15, qq = l >> 4;
            const int c4 = (t * 16 + mm) * (HH / 4) + qq * 2;
            const float4* __restrict__ src = (tid < 128) ? (const float4*)W2 : (const float4*)W3;
            const float4 w0 = src[c4], w1 = src[c4 + 1];
            f16x8 r;
            r[0]=(f16)w0.x; r[1]=(f16)w0.y; r[2]=(f16)w0.z; r[3]=(f16)w0.w;
            r[4]=(f16)w1.x; r[5]=(f16)w1.y; r[6]=(f16)w1.z; r[7]=(f16)w1.w;
            blob16[512 + (tid & 128) + B] = r;
        }
        if (tid < 64) {                         // W4 column fragment
            const int mm = tid & 15, qq = tid >> 4;
            f16x8 r;
            #pragma unroll
            for (int j = 0; j < 8; ++j)
                r[j] = (mm == 0) ? (f16)W4[qq * 8 + j] : (f16)0.0f;
            blob16[768 + tid] = r;
        }
        return;
    }
    const int i = blockIdx.x * 256 + tid;
    if (i < TABQ) {
        const float4 v = ((const float4*)drug)[i];
        f16x4 h;
        h[0]=(f16)v.x; h[1]=(f16)v.y; h[2]=(f16)v.z; h[3]=(f16)v.w;
        ((f16x4*)tab)[i] = h;
    }
}

// pack two f32 -> one dword of 2 f16 (same RNE rounding as scalar casts)
static __device__ __forceinline__ uint32_t pkh(float a, float b) {
    f16x2 h; h[0] = (f16)a; h[1] = (f16)b;
    return __builtin_bit_cast(uint32_t, h);
}
static __device__ __forceinline__ void plswap32(uint32_t &a, uint32_t &b) {
#if __has_builtin(__builtin_amdgcn_permlane32_swap)
    auto r = __builtin_amdgcn_permlane32_swap(a, b, false, false);
    a = r[0]; b = r[1];
#else
    asm volatile("v_permlane32_swap_b32 %0, %1" : "+v"(a), "+v"(b));
#endif
}
static __device__ __forceinline__ void plswap16(uint32_t &a, uint32_t &b) {
#if __has_builtin(__builtin_amdgcn_permlane16_swap)
    auto r = __builtin_amdgcn_permlane16_swap(a, b, false, false);
    a = r[0]; b = r[1];
#else
    asm volatile("v_permlane16_swap_b32 %0, %1" : "+v"(a), "+v"(b));
#endif
}

// Pin a 4-VGPR value against load-sinking/remat (v6 lesson: without this the
// allocator re-issues "loop-invariant" loads inside the loop).
static __device__ __forceinline__ void pin4(f16x8 &w) {
    u32x4 t = __builtin_bit_cast(u32x4, w);
    asm volatile("" : "+v"(t));
    w = __builtin_bit_cast(f16x8, t);
}
static __device__ __forceinline__ void pin4f(f32x4 &w) {
    asm volatile("" : "+v"(w));
}

// Inter-layer transition, all in-register (verified in v5). Input: swapped
// MFMA output, lane (m,q): a0[r]=h[m][4q+r], a1[r]=h[m][16+4q+r]. Output:
// next layer's B-fragment, lane (m,q) holds relu(h)[m][8q..8q+7].
static __device__ __forceinline__ f16x8 transition(f32x4 a0, f32x4 a1) {
    uint32_t u0 = pkh(fmaxf(a0[0], 0.f), fmaxf(a0[1], 0.f));
    uint32_t u1 = pkh(fmaxf(a0[2], 0.f), fmaxf(a0[3], 0.f));
    uint32_t v0 = pkh(fmaxf(a1[0], 0.f), fmaxf(a1[1], 0.f));
    uint32_t v1 = pkh(fmaxf(a1[2], 0.f), fmaxf(a1[3], 0.f));
    plswap32(u0, v0);
    plswap32(u1, v1);
    plswap16(u0, v0);
    plswap16(u1, v1);
    u32x4 d; d[0] = u0; d[1] = u1; d[2] = v0; d[3] = v1;
    return __builtin_bit_cast(f16x8, d);
}

// Main v10: v9 repacked into 1-WAVE BLOCKS + split phase-A MFMA chains.
// Occupancy ceiling is LDS-per-wave: the 12 KB stage fixes the chip at
// floor(160/12) = 13 waves/CU independent of block shape; 256-thread blocks
// quantized that to 12 (3 blocks x 4 waves). Waves have been fully
// independent since v9 (no __syncthreads), so 64-thread blocks lift
// occupancy to 13 waves/CU for free. Phase A's accumulators go from one
// 4-deep dependent MFMA chain to two 2-deep chains + a final f32x4 add,
// trimming ~2 MFMA latencies off the exposed serial path.
// All v9 pipeline invariants kept: DMAs issued right after phase A retires
// the stage reads, flight covered by B-D; loop-top vmcnt(3) (3 younger VMEM
// ops: ed prefetch + result store + label store); sched_barrier fences pin
// VMEM order; weights/biases pinned in registers; no LDS traffic outside
// phase A's stage reads.
__global__ __launch_bounds__(64, 3)
void synergy_main(const f16* __restrict__ tab, const int* __restrict__ edges,
                  const float* __restrict__ b1, const float* __restrict__ b2,
                  const float* __restrict__ b3, const float* __restrict__ b4,
                  float* __restrict__ out, int E, int NG)
{
    __shared__ __align__(16) f16 stage[6144];   // 12 KiB: 48 rows x 256 B

    const int lane = threadIdx.x & 63;
    const int m    = lane & 15;
    const int q    = lane >> 4;

    const char* __restrict__ tabB   = (const char*)tab;
    const f16x8* __restrict__ blobG = (const f16x8*)(tabB + BLOB_OFF);

    const int WSTR = (int)gridDim.x;
    int g = (int)blockIdx.x;
    if (g >= NG) return;

    // ---- weights in registers (loaded once, pinned against sinking)
    f16x8 w1a[4], w1b[4];
    #pragma unroll
    for (int f = 0; f < 4; ++f) {
        w1a[f] = blobG[f * 64 + lane];
        w1b[f] = blobG[256 + f * 64 + lane];
    }
    f16x8 w2a = blobG[512 + lane], w2b = blobG[576 + lane];
    f16x8 w3a = blobG[640 + lane], w3b = blobG[704 + lane];
    f16x8 wf4 = blobG[768 + lane];
    #pragma unroll
    for (int f = 0; f < 4; ++f) { pin4(w1a[f]); pin4(w1b[f]); }
    pin4(w2a); pin4(w2b); pin4(w3a); pin4(w3b); pin4(wf4);

    // ---- biases in registers: lane (m,q) needs b[4q+r] and b[16+4q+r]
    f32x4 bb1a = *(const f32x4*)(b1 + 4 * q), bb1b = *(const f32x4*)(b1 + 16 + 4 * q);
    f32x4 bb2a = *(const f32x4*)(b2 + 4 * q), bb2b = *(const f32x4*)(b2 + 16 + 4 * q);
    f32x4 bb3a = *(const f32x4*)(b3 + 4 * q), bb3b = *(const f32x4*)(b3 + 16 + 4 * q);
    pin4f(bb1a); pin4f(bb1b); pin4f(bb2a); pin4f(bb2b); pin4f(bb3a); pin4f(bb3b);
    const float b4v = b4[0];

    f16* __restrict__ stg = stage;
    const int4* __restrict__ edges4 = (const int4*)edges;

    auto load_ed = [&](int gg) -> int4 {
        int e = (gg << 4) + m;
        e = (e < E) ? e : (E - 1);
        return edges4[e];
    };
    // Rotation-swizzled gather: DMA (t,gg) -> lane 16q+m stages row 4gg+q,
    // slot m, fetching global segment (m + 4gg + q) & 15 of that row.
    // Each instruction reads 4 CONTIGUOUS 256B rows -> coalescer-merged.
    auto issue_dma = [&](const int4 ed) {
        int rowb[12];
        #pragma unroll
        for (int gg = 0; gg < 4; ++gg) {
            const int src = 4 * gg + q;
            rowb[0 * 4 + gg] = __shfl(ed.x, src, 64) << 8;
            rowb[1 * 4 + gg] = __shfl(ed.y, src, 64) << 8;
            rowb[2 * 4 + gg] = __shfl(ed.z, src, 64) << 8;
        }
        __builtin_amdgcn_sched_barrier(0);
        #pragma unroll
        for (int t = 0; t < 3; ++t)
            #pragma unroll
            for (int gg = 0; gg < 4; ++gg) {
                const int seg16 = ((m + 4 * gg + q) & 15) << 4;
                __builtin_amdgcn_global_load_lds(
                    GL1(tabB + (size_t)(rowb[t * 4 + gg] + seg16)),
                    LDS3((char*)stg + (t * 16 + 4 * gg) * 256), 16, 0, 0);
            }
        __builtin_amdgcn_sched_barrier(0);   // nothing crosses the DMA cluster
    };

    // ---- prologue: group g staged and fully drained once
    int4 ed_cur = load_ed(g);
    issue_dma(ed_cur);
    int gn = g + WSTR;
    int4 ed_nxt = load_ed((gn < NG) ? gn : g);
    __builtin_amdgcn_s_waitcnt(0x0F70);          // vmcnt(0): one-time drain
    __builtin_amdgcn_sched_barrier(0);

    for (;;) {
        // steady state: all 12 DMAs are older than exactly 3 VMEM ops
        __builtin_amdgcn_s_waitcnt(0x0F73);      // vmcnt(3): stage landed
        __builtin_amdgcn_sched_barrier(0);

        // ---- Phase A: L1 (8 MFMAs, K=128, swapped: D = W1.h^T); reads stage
        // Two 2-deep chains per accumulator instead of one 4-deep chain.
        f32x4 acc0 = bb1a, acx0 = {0.f, 0.f, 0.f, 0.f};
        f32x4 acc1 = bb1b, acx1 = {0.f, 0.f, 0.f, 0.f};
        #pragma unroll
        for (int f = 0; f < 4; ++f) {
            const int slot = (((f * 4 + q) - m) & 15) << 3;
            const f16x8 v0 = *(const f16x8*)(stg + (0 * 16 + m) * 128 + slot);
            const f16x8 v1 = *(const f16x8*)(stg + (1 * 16 + m) * 128 + slot);
            const f16x8 v2 = *(const f16x8*)(stg + (2 * 16 + m) * 128 + slot);
            const f16x8 p = v0 * v1 * v2;
            if (f < 2) {
                acc0 = __builtin_amdgcn_mfma_f32_16x16x32_f16(w1a[f], p, acc0, 0, 0, 0);
                acc1 = __builtin_amdgcn_mfma_f32_16x16x32_f16(w1b[f], p, acc1, 0, 0, 0);
            } else {
                acx0 = __builtin_amdgcn_mfma_f32_16x16x32_f16(w1a[f], p, acx0, 0, 0, 0);
                acx1 = __builtin_amdgcn_mfma_f32_16x16x32_f16(w1b[f], p, acx1, 0, 0, 0);
            }
        }
        acc0 += acx0;
        acc1 += acx1;
        const f16x8 h1 = transition(acc0, acc1);
        // stage reads are retired (MFMAs consumed them) -> safe to overwrite

        // ---- async stage refill: flight covered by phases B-D (same wave)
        const bool last = (gn >= NG);
        const int gf = gn + WSTR;
        int4 ed_fut = ed_nxt;
        if (!last) {
            issue_dma(ed_nxt);                   // 12 DMAs
            ed_fut = load_ed((gf < NG) ? gf : g); // younger op #1
        }

        // ---- Phase B: L2 (pure register)
        f32x4 c0 = bb2a;
        f32x4 c1 = bb2b;
        c0 = __builtin_amdgcn_mfma_f32_16x16x32_f16(w2a, h1, c0, 0, 0, 0);
        c1 = __builtin_amdgcn_mfma_f32_16x16x32_f16(w2b, h1, c1, 0, 0, 0);
        const f16x8 h2 = transition(c0, c1);

        // ---- Phase C: L3 (pure register)
        f32x4 d0 = bb3a;
        f32x4 d1 = bb3b;
        d0 = __builtin_amdgcn_mfma_f32_16x16x32_f16(w3a, h2, d0, 0, 0, 0);
        d1 = __builtin_amdgcn_mfma_f32_16x16x32_f16(w3b, h2, d1, 0, 0, 0);
        const f16x8 h3 = transition(d0, d1);

        // ---- Phase D: L4 vs zero-padded W4 column; lanes q==0 hold z[m]
        {
            f32x4 z = {b4v, b4v, b4v, b4v};
            z = __builtin_amdgcn_mfma_f32_16x16x32_f16(wf4, h3, z, 0, 0, 0);
            if (q == 0) {                        // younger op #2
                const int e0 = (g << 4) + m;
                if (e0 < E) out[e0] = 1.0f / (1.0f + __expf(-z[0]));
            }
        }
        // label pass-through                    // younger op #3
        const int eL = (g << 4) + lane;
        if (lane < 16 && eL < E) out[E + eL] = (float)ed_cur.w;

        if (last) break;
        g = gn; gn = gf; ed_cur = ed_nxt; ed_nxt = ed_fut;
    }
}

extern "C" void kernel_launch(void* const* d_in, const int* in_sizes, int n_in,
                              void* d_out, int out_size, void* d_ws, size_t ws_size,
                              hipStream_t stream)
{
    const float* drug  = (const float*)d_in[0];
    // d_in[1] (cell_hidden_out), d_in[3] (proj_W), d_in[4] (proj_b): dead code
    const int*   edges = (const int*)d_in[2];
    const float* W1 = (const float*)d_in[5];
    const float* b1 = (const float*)d_in[6];
    const float* W2 = (const float*)d_in[7];
    const float* b2 = (const float*)d_in[8];
    const float* W3 = (const float*)d_in[9];
    const float* b3 = (const float*)d_in[10];
    const float* W4 = (const float*)d_in[11];
    const float* b4 = (const float*)d_in[12];
    float* out = (float*)d_out;
    f16*   tab = (f16*)d_ws;   // [0,1MB): f16 table; [1MB,+13KB): weight blob

    const int E  = in_sizes[2] / 4;
    const int NG = (E + 15) / 16;

    hipLaunchKernelGGL(synergy_prepass, dim3(513), dim3(256), 0, stream,
                       drug, W1, W2, W3, W4, tab);
    int blocks = NG;
    if (blocks > 3328) blocks = 3328;        // 13 x 12KB blocks/CU x 256 CUs
    hipLaunchKernelGGL(synergy_main, dim3(blocks), dim3(64), 0, stream,
                       tab, edges, b1, b2, b3, b4, out, E, NG);
}

// Round 10
// 112.204 us; speedup vs baseline: 1.0372x; 1.0372x over previous
//
#include <hip/hip_runtime.h>
#include <stdint.h>

#define DD 128                 // drug feature dim
#define HH 32                  // hidden dim
#define TABQ (4096 * DD / 4)   // float4 count of drug table
#define BLOB_OFF (1u << 20)    // weight fragment blob offset inside d_ws (bytes)

typedef _Float16 f16;
typedef _Float16 f16x2 __attribute__((ext_vector_type(2)));
typedef _Float16 f16x4 __attribute__((ext_vector_type(4)));
typedef _Float16 f16x8 __attribute__((ext_vector_type(8)));
typedef float    f32x4 __attribute__((ext_vector_type(4)));
typedef uint32_t u32x4 __attribute__((ext_vector_type(4)));

#define GL1(p)  ((const __attribute__((address_space(1))) void*)(p))
#define LDS3(p) ((__attribute__((address_space(3))) void*)(p))

// Pre-pass: (a) drug table f32->f16 (blocks 0..511); (b) weight-fragment blob
// at ws+1MB (block 512): W1 slots 0..511, W2 512..639, W3 640..767,
// W4-column-fragment 768..831. Fragments are role-symmetric (A vs B operand),
// so the swapped-MFMA main kernel reuses them unchanged.
__global__ __launch_bounds__(256)
void synergy_prepass(const float* __restrict__ drug,
                     const float* __restrict__ W1, const float* __restrict__ W2,
                     const float* __restrict__ W3, const float* __restrict__ W4,
                     f16* __restrict__ tab)
{
    const int tid = threadIdx.x;
    if ((int)blockIdx.x == 512) {
        f16x8* __restrict__ blob16 = (f16x8*)((char*)tab + BLOB_OFF);
        const float4* __restrict__ W1v = (const float4*)W1;
        #pragma unroll
        for (int p = 0; p < 2; ++p) {
            const int S = p * 256 + tid;
            const int t = S >> 8, f = (S >> 6) & 3, l = S & 63;
            const int mm = l & 15, qq = l >> 4;
            const int c4 = (t * 16 + mm) * (DD / 4) + f * 8 + qq * 2;
            const float4 w0 = W1v[c4], w1 = W1v[c4 + 1];
            f16x8 r;
            r[0]=(f16)w0.x; r[1]=(f16)w0.y; r[2]=(f16)w0.z; r[3]=(f16)w0.w;
            r[4]=(f16)w1.x; r[5]=(f16)w1.y; r[6]=(f16)w1.z; r[7]=(f16)w1.w;
            blob16[S] = r;
        }
        {
            const int B = tid & 127;
            const int t = B >> 6, l = B & 63;
            const int mm = l & 15, qq = l >> 4;
            const int c4 = (t * 16 + mm) * (HH / 4) + qq * 2;
            const float4* __restrict__ src = (tid < 128) ? (const float4*)W2 : (const float4*)W3;
            const float4 w0 = src[c4], w1 = src[c4 + 1];
            f16x8 r;
            r[0]=(f16)w0.x; r[1]=(f16)w0.y; r[2]=(f16)w0.z; r[3]=(f16)w0.w;
            r[4]=(f16)w1.x; r[5]=(f16)w1.y; r[6]=(f16)w1.z; r[7]=(f16)w1.w;
            blob16[512 + (tid & 128) + B] = r;
        }
        if (tid < 64) {                         // W4 column fragment
            const int mm = tid & 15, qq = tid >> 4;
            f16x8 r;
            #pragma unroll
            for (int j = 0; j < 8; ++j)
                r[j] = (mm == 0) ? (f16)W4[qq * 8 + j] : (f16)0.0f;
            blob16[768 + tid] = r;
        }
        return;
    }
    const int i = blockIdx.x * 256 + tid;
    if (i < TABQ) {
        const float4 v = ((const float4*)drug)[i];
        f16x4 h;
        h[0]=(f16)v.x; h[1]=(f16)v.y; h[2]=(f16)v.z; h[3]=(f16)v.w;
        ((f16x4*)tab)[i] = h;
    }
}

// pack two f32 -> one dword of 2 f16 (same RNE rounding as scalar casts)
static __device__ __forceinline__ uint32_t pkh(float a, float b) {
    f16x2 h; h[0] = (f16)a; h[1] = (f16)b;
    return __builtin_bit_cast(uint32_t, h);
}
static __device__ __forceinline__ void plswap32(uint32_t &a, uint32_t &b) {
#if __has_builtin(__builtin_amdgcn_permlane32_swap)
    auto r = __builtin_amdgcn_permlane32_swap(a, b, false, false);
    a = r[0]; b = r[1];
#else
    asm volatile("v_permlane32_swap_b32 %0, %1" : "+v"(a), "+v"(b));
#endif
}
static __device__ __forceinline__ void plswap16(uint32_t &a, uint32_t &b) {
#if __has_builtin(__builtin_amdgcn_permlane16_swap)
    auto r = __builtin_amdgcn_permlane16_swap(a, b, false, false);
    a = r[0]; b = r[1];
#else
    asm volatile("v_permlane16_swap_b32 %0, %1" : "+v"(a), "+v"(b));
#endif
}

// Pin a 4-VGPR value against load-sinking/remat (v6 lesson: without this the
// allocator re-issues "loop-invariant" loads inside the loop).
static __device__ __forceinline__ void pin4(f16x8 &w) {
    u32x4 t = __builtin_bit_cast(u32x4, w);
    asm volatile("" : "+v"(t));
    w = __builtin_bit_cast(f16x8, t);
}
static __device__ __forceinline__ void pin4f(f32x4 &w) {
    asm volatile("" : "+v"(w));
}

// Inter-layer transition, all in-register (verified in v5). Input: swapped
// MFMA output, lane (m,q): a0[r]=h[m][4q+r], a1[r]=h[m][16+4q+r]. Output:
// next layer's B-fragment, lane (m,q) holds relu(h)[m][8q..8q+7].
static __device__ __forceinline__ f16x8 transition(f32x4 a0, f32x4 a1) {
    uint32_t u0 = pkh(fmaxf(a0[0], 0.f), fmaxf(a0[1], 0.f));
    uint32_t u1 = pkh(fmaxf(a0[2], 0.f), fmaxf(a0[3], 0.f));
    uint32_t v0 = pkh(fmaxf(a1[0], 0.f), fmaxf(a1[1], 0.f));
    uint32_t v1 = pkh(fmaxf(a1[2], 0.f), fmaxf(a1[3], 0.f));
    plswap32(u0, v0);
    plswap32(u1, v1);
    plswap16(u0, v0);
    plswap16(u1, v1);
    u32x4 d; d[0] = u0; d[1] = u1; d[2] = v0; d[3] = v1;
    return __builtin_bit_cast(f16x8, d);
}

// Main v11: v9 (the best measured config: 256-thr blocks, 3 blk/CU) with ONE
// change -- the refill DMAs issue BEFORE phase A's MFMAs, not after.
// The only true dependence for overwriting the stage is that the 12 stage
// ds_reads have RETIRED (lgkmcnt(0)); the MFMAs consume register copies.
// So: read stage -> p[0..3] regs, s_waitcnt lgkmcnt(0) + sched_barrier(0),
// issue 12 DMAs + ed prefetch, THEN run the MFMA/permlane chain. This adds
// phase A's ~400 cyc of MFMA+transition to the DMA-flight coverage window
// (previously only B-D covered it), shrinking the loop-top vmcnt(3) stall.
// v10's 1-wave-block repack REGRESSED (+4.6us; LDS/WG-slot quantization
// suspected) -- reverted to v9 packing.
// vmcnt accounting unchanged: per iteration exactly 3 VMEM ops are younger
// than the last DMA (ed prefetch + result store + label store), so loop-top
// vmcnt(3) == "stage landed" without waiting on store-acks.
__global__ __launch_bounds__(256, 3)
void synergy_main(const f16* __restrict__ tab, const int* __restrict__ edges,
                  const float* __restrict__ b1, const float* __restrict__ b2,
                  const float* __restrict__ b3, const float* __restrict__ b4,
                  float* __restrict__ out, int E, int NG)
{
    __shared__ __align__(16) f16 stage[4][6144];   // 48 KiB: 48 rows x 256 B per wave

    const int tid  = threadIdx.x;
    const int wave = tid >> 6;
    const int lane = tid & 63;
    const int m    = lane & 15;
    const int q    = lane >> 4;

    const char* __restrict__ tabB   = (const char*)tab;
    const f16x8* __restrict__ blobG = (const f16x8*)(tabB + BLOB_OFF);

    const int WSTR = (int)gridDim.x * 4;
    int g = (int)blockIdx.x * 4 + wave;
    if (g >= NG) return;

    // ---- weights in registers (loaded once, pinned against sinking)
    f16x8 w1a[4], w1b[4];
    #pragma unroll
    for (int f = 0; f < 4; ++f) {
        w1a[f] = blobG[f * 64 + lane];
        w1b[f] = blobG[256 + f * 64 + lane];
    }
    f16x8 w2a = blobG[512 + lane], w2b = blobG[576 + lane];
    f16x8 w3a = blobG[640 + lane], w3b = blobG[704 + lane];
    f16x8 wf4 = blobG[768 + lane];
    #pragma unroll
    for (int f = 0; f < 4; ++f) { pin4(w1a[f]); pin4(w1b[f]); }
    pin4(w2a); pin4(w2b); pin4(w3a); pin4(w3b); pin4(wf4);

    // ---- biases in registers: lane (m,q) needs b[4q+r] and b[16+4q+r]
    f32x4 bb1a = *(const f32x4*)(b1 + 4 * q), bb1b = *(const f32x4*)(b1 + 16 + 4 * q);
    f32x4 bb2a = *(const f32x4*)(b2 + 4 * q), bb2b = *(const f32x4*)(b2 + 16 + 4 * q);
    f32x4 bb3a = *(const f32x4*)(b3 + 4 * q), bb3b = *(const f32x4*)(b3 + 16 + 4 * q);
    pin4f(bb1a); pin4f(bb1b); pin4f(bb2a); pin4f(bb2b); pin4f(bb3a); pin4f(bb3b);
    const float b4v = b4[0];

    f16* __restrict__ stg = stage[wave];
    const int4* __restrict__ edges4 = (const int4*)edges;

    auto load_ed = [&](int gg) -> int4 {
        int e = (gg << 4) + m;
        e = (e < E) ? e : (E - 1);
        return edges4[e];
    };
    // Rotation-swizzled gather: DMA (t,gg) -> lane 16q+m stages row 4gg+q,
    // slot m, fetching global segment (m + 4gg + q) & 15 of that row.
    // Each instruction reads 4 CONTIGUOUS 256B rows -> coalescer-merged.
    auto issue_dma = [&](const int4 ed) {
        int rowb[12];
        #pragma unroll
        for (int gg = 0; gg < 4; ++gg) {
            const int src = 4 * gg + q;
            rowb[0 * 4 + gg] = __shfl(ed.x, src, 64) << 8;
            rowb[1 * 4 + gg] = __shfl(ed.y, src, 64) << 8;
            rowb[2 * 4 + gg] = __shfl(ed.z, src, 64) << 8;
        }
        __builtin_amdgcn_sched_barrier(0);
        #pragma unroll
        for (int t = 0; t < 3; ++t)
            #pragma unroll
            for (int gg = 0; gg < 4; ++gg) {
                const int seg16 = ((m + 4 * gg + q) & 15) << 4;
                __builtin_amdgcn_global_load_lds(
                    GL1(tabB + (size_t)(rowb[t * 4 + gg] + seg16)),
                    LDS3((char*)stg + (t * 16 + 4 * gg) * 256), 16, 0, 0);
            }
        __builtin_amdgcn_sched_barrier(0);   // nothing crosses the DMA cluster
    };

    // ---- prologue: group g staged and fully drained once
    int4 ed_cur = load_ed(g);
    issue_dma(ed_cur);
    int gn = g + WSTR;
    int4 ed_nxt = load_ed((gn < NG) ? gn : g);
    __builtin_amdgcn_s_waitcnt(0x0F70);          // vmcnt(0): one-time drain
    __builtin_amdgcn_sched_barrier(0);

    for (;;) {
        // steady state: all 12 DMAs are older than exactly 3 VMEM ops
        __builtin_amdgcn_s_waitcnt(0x0F73);      // vmcnt(3): stage landed
        __builtin_amdgcn_sched_barrier(0);

        // ---- Phase A part 1: stage -> registers (12 ds_reads, 8 pk-muls)
        f16x8 p[4];
        #pragma unroll
        for (int f = 0; f < 4; ++f) {
            const int slot = (((f * 4 + q) - m) & 15) << 3;
            const f16x8 v0 = *(const f16x8*)(stg + (0 * 16 + m) * 128 + slot);
            const f16x8 v1 = *(const f16x8*)(stg + (1 * 16 + m) * 128 + slot);
            const f16x8 v2 = *(const f16x8*)(stg + (2 * 16 + m) * 128 + slot);
            p[f] = v0 * v1 * v2;
        }
        asm volatile("s_waitcnt lgkmcnt(0)" ::: "memory"); // stage reads retired
        __builtin_amdgcn_sched_barrier(0);

        // ---- async stage refill EARLY: flight covered by A's MFMAs + B-D
        const bool last = (gn >= NG);
        const int gf = gn + WSTR;
        int4 ed_fut = ed_nxt;
        if (!last) {
            issue_dma(ed_nxt);                   // 12 DMAs
            ed_fut = load_ed((gf < NG) ? gf : g); // younger op #1
        }

        // ---- Phase A part 2: L1 (8 MFMAs, K=128, swapped: D = W1.h^T)
        f32x4 acc0 = bb1a;
        f32x4 acc1 = bb1b;
        #pragma unroll
        for (int f = 0; f < 4; ++f) {
            acc0 = __builtin_amdgcn_mfma_f32_16x16x32_f16(w1a[f], p[f], acc0, 0, 0, 0);
            acc1 = __builtin_amdgcn_mfma_f32_16x16x32_f16(w1b[f], p[f], acc1, 0, 0, 0);
        }
        const f16x8 h1 = transition(acc0, acc1);

        // ---- Phase B: L2 (pure register)
        f32x4 c0 = bb2a;
        f32x4 c1 = bb2b;
        c0 = __builtin_amdgcn_mfma_f32_16x16x32_f16(w2a, h1, c0, 0, 0, 0);
        c1 = __builtin_amdgcn_mfma_f32_16x16x32_f16(w2b, h1, c1, 0, 0, 0);
        const f16x8 h2 = transition(c0, c1);

        // ---- Phase C: L3 (pure register)
        f32x4 d0 = bb3a;
        f32x4 d1 = bb3b;
        d0 = __builtin_amdgcn_mfma_f32_16x16x32_f16(w3a, h2, d0, 0, 0, 0);
        d1 = __builtin_amdgcn_mfma_f32_16x16x32_f16(w3b, h2, d1, 0, 0, 0);
        const f16x8 h3 = transition(d0, d1);

        // ---- Phase D: L4 vs zero-padded W4 column; lanes q==0 hold z[m]
        {
            f32x4 z = {b4v, b4v, b4v, b4v};
            z = __builtin_amdgcn_mfma_f32_16x16x32_f16(wf4, h3, z, 0, 0, 0);
            if (q == 0) {                        // younger op #2
                const int e0 = (g << 4) + m;
                if (e0 < E) out[e0] = 1.0f / (1.0f + __expf(-z[0]));
            }
        }
        // label pass-through                    // younger op #3
        const int eL = (g << 4) + lane;
        if (lane < 16 && eL < E) out[E + eL] = (float)ed_cur.w;

        if (last) break;
        g = gn; gn = gf; ed_cur = ed_nxt; ed_nxt = ed_fut;
    }
}

extern "C" void kernel_launch(void* const* d_in, const int* in_sizes, int n_in,
                              void* d_out, int out_size, void* d_ws, size_t ws_size,
                              hipStream_t stream)
{
    const float* drug  = (const float*)d_in[0];
    // d_in[1] (cell_hidden_out), d_in[3] (proj_W), d_in[4] (proj_b): dead code
    const int*   edges = (const int*)d_in[2];
    const float* W1 = (const float*)d_in[5];
    const float* b1 = (const float*)d_in[6];
    const float* W2 = (const float*)d_in[7];
    const float* b2 = (const float*)d_in[8];
    const float* W3 = (const float*)d_in[9];
    const float* b3 = (const float*)d_in[10];
    const float* W4 = (const float*)d_in[11];
    const float* b4 = (const float*)d_in[12];
    float* out = (float*)d_out;
    f16*   tab = (f16*)d_ws;   // [0,1MB): f16 table; [1MB,+13KB): weight blob

    const int E  = in_sizes[2] / 4;
    const int NG = (E + 15) / 16;

    hipLaunchKernelGGL(synergy_prepass, dim3(513), dim3(256), 0, stream,
                       drug, W1, W2, W3, W4, tab);
    int blocks = (NG + 3) / 4;
    if (blocks > 768) blocks = 768;          // 3 blocks/CU x 256 CUs
    hipLaunchKernelGGL(synergy_main, dim3(blocks), dim3(256), 0, stream,
                       tab, edges, b1, b2, b3, b4, out, E, NG);
}

// Round 11
// 111.891 us; speedup vs baseline: 1.0401x; 1.0028x over previous
//
#include <hip/hip_runtime.h>
#include <stdint.h>

#define DD 128                 // drug feature dim
#define HH 32                  // hidden dim
#define TABQ (4096 * DD / 4)   // float4 count of drug table
#define BLOB_OFF (1u << 20)    // weight fragment blob offset inside d_ws (bytes)

typedef _Float16 f16;
typedef _Float16 f16x2 __attribute__((ext_vector_type(2)));
typedef _Float16 f16x4 __attribute__((ext_vector_type(4)));
typedef _Float16 f16x8 __attribute__((ext_vector_type(8)));
typedef float    f32x4 __attribute__((ext_vector_type(4)));
typedef uint32_t u32x4 __attribute__((ext_vector_type(4)));

#define GL1(p)  ((const __attribute__((address_space(1))) void*)(p))
#define LDS3(p) ((__attribute__((address_space(3))) void*)(p))

// Pre-pass: (a) drug table f32->f16 (blocks 0..511); (b) weight-fragment blob
// at ws+1MB (block 512): W1 slots 0..511, W2 512..639, W3 640..767,
// W4-column-fragment 768..831. Fragments are role-symmetric (A vs B operand),
// so the swapped-MFMA main kernel reuses them unchanged.
__global__ __launch_bounds__(256)
void synergy_prepass(const float* __restrict__ drug,
                     const float* __restrict__ W1, const float* __restrict__ W2,
                     const float* __restrict__ W3, const float* __restrict__ W4,
                     f16* __restrict__ tab)
{
    const int tid = threadIdx.x;
    if ((int)blockIdx.x == 512) {
        f16x8* __restrict__ blob16 = (f16x8*)((char*)tab + BLOB_OFF);
        const float4* __restrict__ W1v = (const float4*)W1;
        #pragma unroll
        for (int p = 0; p < 2; ++p) {
            const int S = p * 256 + tid;
            const int t = S >> 8, f = (S >> 6) & 3, l = S & 63;
            const int mm = l & 15, qq = l >> 4;
            const int c4 = (t * 16 + mm) * (DD / 4) + f * 8 + qq * 2;
            const float4 w0 = W1v[c4], w1 = W1v[c4 + 1];
            f16x8 r;
            r[0]=(f16)w0.x; r[1]=(f16)w0.y; r[2]=(f16)w0.z; r[3]=(f16)w0.w;
            r[4]=(f16)w1.x; r[5]=(f16)w1.y; r[6]=(f16)w1.z; r[7]=(f16)w1.w;
            blob16[S] = r;
        }
        {
            const int B = tid & 127;
            const int t = B >> 6, l = B & 63;
            const int mm = l & 15, qq = l >> 4;
            const int c4 = (t * 16 + mm) * (HH / 4) + qq * 2;
            const float4* __restrict__ src = (tid < 128) ? (const float4*)W2 : (const float4*)W3;
            const float4 w0 = src[c4], w1 = src[c4 + 1];
            f16x8 r;
            r[0]=(f16)w0.x; r[1]=(f16)w0.y; r[2]=(f16)w0.z; r[3]=(f16)w0.w;
            r[4]=(f16)w1.x; r[5]=(f16)w1.y; r[6]=(f16)w1.z; r[7]=(f16)w1.w;
            blob16[512 + (tid & 128) + B] = r;
        }
        if (tid < 64) {                         // W4 column fragment
            const int mm = tid & 15, qq = tid >> 4;
            f16x8 r;
            #pragma unroll
            for (int j = 0; j < 8; ++j)
                r[j] = (mm == 0) ? (f16)W4[qq * 8 + j] : (f16)0.0f;
            blob16[768 + tid] = r;
        }
        return;
    }
    const int i = blockIdx.x * 256 + tid;
    if (i < TABQ) {
        const float4 v = ((const float4*)drug)[i];
        f16x4 h;
        h[0]=(f16)v.x; h[1]=(f16)v.y; h[2]=(f16)v.z; h[3]=(f16)v.w;
        ((f16x4*)tab)[i] = h;
    }
}

// pack two f32 -> one dword of 2 f16 (same RNE rounding as scalar casts)
static __device__ __forceinline__ uint32_t pkh(float a, float b) {
    f16x2 h; h[0] = (f16)a; h[1] = (f16)b;
    return __builtin_bit_cast(uint32_t, h);
}
static __device__ __forceinline__ void plswap32(uint32_t &a, uint32_t &b) {
#if __has_builtin(__builtin_amdgcn_permlane32_swap)
    auto r = __builtin_amdgcn_permlane32_swap(a, b, false, false);
    a = r[0]; b = r[1];
#else
    asm volatile("v_permlane32_swap_b32 %0, %1" : "+v"(a), "+v"(b));
#endif
}
static __device__ __forceinline__ void plswap16(uint32_t &a, uint32_t &b) {
#if __has_builtin(__builtin_amdgcn_permlane16_swap)
    auto r = __builtin_amdgcn_permlane16_swap(a, b, false, false);
    a = r[0]; b = r[1];
#else
    asm volatile("v_permlane16_swap_b32 %0, %1" : "+v"(a), "+v"(b));
#endif
}

// Pin a 4-VGPR value against load-sinking/remat (v6 lesson: without this the
// allocator re-issues "loop-invariant" loads inside the loop).
static __device__ __forceinline__ void pin4(f16x8 &w) {
    u32x4 t = __builtin_bit_cast(u32x4, w);
    asm volatile("" : "+v"(t));
    w = __builtin_bit_cast(f16x8, t);
}
static __device__ __forceinline__ void pin4f(f32x4 &w) {
    asm volatile("" : "+v"(w));
}

// Inter-layer transition, all in-register (verified in v5). Input: swapped
// MFMA output, lane (m,q): a0[r]=h[m][4q+r], a1[r]=h[m][16+4q+r]. Output:
// next layer's B-fragment, lane (m,q) holds relu(h)[m][8q..8q+7].
static __device__ __forceinline__ f16x8 transition(f32x4 a0, f32x4 a1) {
    uint32_t u0 = pkh(fmaxf(a0[0], 0.f), fmaxf(a0[1], 0.f));
    uint32_t u1 = pkh(fmaxf(a0[2], 0.f), fmaxf(a0[3], 0.f));
    uint32_t v0 = pkh(fmaxf(a1[0], 0.f), fmaxf(a1[1], 0.f));
    uint32_t v1 = pkh(fmaxf(a1[2], 0.f), fmaxf(a1[3], 0.f));
    plswap32(u0, v0);
    plswap32(u1, v1);
    plswap16(u0, v0);
    plswap16(u1, v1);
    u32x4 d; d[0] = u0; d[1] = u1; d[2] = v0; d[3] = v1;
    return __builtin_bit_cast(f16x8, d);
}

// Main v12: v11 with the DMA-batch ADDRESS WORK hoisted out of the critical
// path. In v11 the fence->DMA window contained 12 __shfl (= ds_bpermute,
// LDS-pipe ops with lgkm waits) + 12 adds; every cycle there delays DMA #12
// and translates 1:1 into next iteration's loop-top vmcnt(3) stall. The
// offsets depend only on ed_nxt (in registers since 2 iterations back), so
// calc_off() now runs at the LOOP BOTTOM in the previous iteration's B-D
// shadow, keeping 12 ready byte-offsets in VGPRs; issue_dma() is fence ->
// 12 bare global_load_lds -> fence. Addresses are bit-identical to v11.
// vmcnt accounting unchanged: 3 VMEM ops younger than the last DMA
// (ed prefetch + result store + label store) -> loop-top vmcnt(3).
__global__ __launch_bounds__(256, 3)
void synergy_main(const f16* __restrict__ tab, const int* __restrict__ edges,
                  const float* __restrict__ b1, const float* __restrict__ b2,
                  const float* __restrict__ b3, const float* __restrict__ b4,
                  float* __restrict__ out, int E, int NG)
{
    __shared__ __align__(16) f16 stage[4][6144];   // 48 KiB: 48 rows x 256 B per wave

    const int tid  = threadIdx.x;
    const int wave = tid >> 6;
    const int lane = tid & 63;
    const int m    = lane & 15;
    const int q    = lane >> 4;

    const char* __restrict__ tabB   = (const char*)tab;
    const f16x8* __restrict__ blobG = (const f16x8*)(tabB + BLOB_OFF);

    const int WSTR = (int)gridDim.x * 4;
    int g = (int)blockIdx.x * 4 + wave;
    if (g >= NG) return;

    // ---- weights in registers (loaded once, pinned against sinking)
    f16x8 w1a[4], w1b[4];
    #pragma unroll
    for (int f = 0; f < 4; ++f) {
        w1a[f] = blobG[f * 64 + lane];
        w1b[f] = blobG[256 + f * 64 + lane];
    }
    f16x8 w2a = blobG[512 + lane], w2b = blobG[576 + lane];
    f16x8 w3a = blobG[640 + lane], w3b = blobG[704 + lane];
    f16x8 wf4 = blobG[768 + lane];
    #pragma unroll
    for (int f = 0; f < 4; ++f) { pin4(w1a[f]); pin4(w1b[f]); }
    pin4(w2a); pin4(w2b); pin4(w3a); pin4(w3b); pin4(wf4);

    // ---- biases in registers: lane (m,q) needs b[4q+r] and b[16+4q+r]
    f32x4 bb1a = *(const f32x4*)(b1 + 4 * q), bb1b = *(const f32x4*)(b1 + 16 + 4 * q);
    f32x4 bb2a = *(const f32x4*)(b2 + 4 * q), bb2b = *(const f32x4*)(b2 + 16 + 4 * q);
    f32x4 bb3a = *(const f32x4*)(b3 + 4 * q), bb3b = *(const f32x4*)(b3 + 16 + 4 * q);
    pin4f(bb1a); pin4f(bb1b); pin4f(bb2a); pin4f(bb2b); pin4f(bb3a); pin4f(bb3b);
    const float b4v = b4[0];

    f16* __restrict__ stg = stage[wave];
    const int4* __restrict__ edges4 = (const int4*)edges;

    auto load_ed = [&](int gg) -> int4 {
        int e = (gg << 4) + m;
        e = (e < E) ? e : (E - 1);
        return edges4[e];
    };
    // Rotation-swizzled gather addressing: DMA (t,gg) -> lane 16q+m stages
    // row 4gg+q, slot m, fetching global segment (m + 4gg + q) & 15.
    // Computed AHEAD of time (12 bpermutes + adds) into 12 persistent VGPRs.
    auto calc_off = [&](const int4 ed, int* off) {
        #pragma unroll
        for (int gg = 0; gg < 4; ++gg) {
            const int src   = 4 * gg + q;
            const int seg16 = ((m + 4 * gg + q) & 15) << 4;
            off[0 * 4 + gg] = (__shfl(ed.x, src, 64) << 8) + seg16;
            off[1 * 4 + gg] = (__shfl(ed.y, src, 64) << 8) + seg16;
            off[2 * 4 + gg] = (__shfl(ed.z, src, 64) << 8) + seg16;
        }
    };
    // Pure DMA issue: 12 bare global_load_lds, each reading 4 contiguous
    // 256B rows (coalescer-merged).
    auto issue_dma = [&](const int* off) {
        __builtin_amdgcn_sched_barrier(0);
        #pragma unroll
        for (int t = 0; t < 3; ++t)
            #pragma unroll
            for (int gg = 0; gg < 4; ++gg)
                __builtin_amdgcn_global_load_lds(
                    GL1(tabB + (size_t)off[t * 4 + gg]),
                    LDS3((char*)stg + (t * 16 + 4 * gg) * 256), 16, 0, 0);
        __builtin_amdgcn_sched_barrier(0);   // nothing crosses the DMA cluster
    };

    // ---- prologue: group g staged; offsets for group g+WSTR precomputed
    int off_buf[12];
    int4 ed_cur = load_ed(g);
    calc_off(ed_cur, off_buf);
    issue_dma(off_buf);
    int gn = g + WSTR;
    int4 ed_nxt = load_ed((gn < NG) ? gn : g);
    calc_off(ed_nxt, off_buf);                   // iteration 0's refill target
    __builtin_amdgcn_s_waitcnt(0x0F70);          // vmcnt(0): one-time drain
    __builtin_amdgcn_sched_barrier(0);

    for (;;) {
        // steady state: all 12 DMAs are older than exactly 3 VMEM ops
        __builtin_amdgcn_s_waitcnt(0x0F73);      // vmcnt(3): stage landed
        __builtin_amdgcn_sched_barrier(0);

        // ---- Phase A part 1: stage -> registers (12 ds_reads, 8 pk-muls)
        f16x8 p[4];
        #pragma unroll
        for (int f = 0; f < 4; ++f) {
            const int slot = (((f * 4 + q) - m) & 15) << 3;
            const f16x8 v0 = *(const f16x8*)(stg + (0 * 16 + m) * 128 + slot);
            const f16x8 v1 = *(const f16x8*)(stg + (1 * 16 + m) * 128 + slot);
            const f16x8 v2 = *(const f16x8*)(stg + (2 * 16 + m) * 128 + slot);
            p[f] = v0 * v1 * v2;
        }
        asm volatile("s_waitcnt lgkmcnt(0)" ::: "memory"); // stage reads retired
        __builtin_amdgcn_sched_barrier(0);

        // ---- async stage refill: pure issue (offsets precomputed last iter)
        const bool last = (gn >= NG);
        const int gf = gn + WSTR;
        int4 ed_fut = ed_nxt;
        if (!last) {
            issue_dma(off_buf);                  // 12 DMAs, zero prelude
            ed_fut = load_ed((gf < NG) ? gf : g); // younger op #1
        }

        // ---- Phase A part 2: L1 (8 MFMAs, K=128, swapped: D = W1.h^T)
        f32x4 acc0 = bb1a;
        f32x4 acc1 = bb1b;
        #pragma unroll
        for (int f = 0; f < 4; ++f) {
            acc0 = __builtin_amdgcn_mfma_f32_16x16x32_f16(w1a[f], p[f], acc0, 0, 0, 0);
            acc1 = __builtin_amdgcn_mfma_f32_16x16x32_f16(w1b[f], p[f], acc1, 0, 0, 0);
        }
        const f16x8 h1 = transition(acc0, acc1);

        // ---- Phase B: L2 (pure register)
        f32x4 c0 = bb2a;
        f32x4 c1 = bb2b;
        c0 = __builtin_amdgcn_mfma_f32_16x16x32_f16(w2a, h1, c0, 0, 0, 0);
        c1 = __builtin_amdgcn_mfma_f32_16x16x32_f16(w2b, h1, c1, 0, 0, 0);
        const f16x8 h2 = transition(c0, c1);

        // ---- Phase C: L3 (pure register)
        f32x4 d0 = bb3a;
        f32x4 d1 = bb3b;
        d0 = __builtin_amdgcn_mfma_f32_16x16x32_f16(w3a, h2, d0, 0, 0, 0);
        d1 = __builtin_amdgcn_mfma_f32_16x16x32_f16(w3b, h2, d1, 0, 0, 0);
        const f16x8 h3 = transition(d0, d1);

        // ---- Phase D: L4 vs zero-padded W4 column; lanes q==0 hold z[m]
        {
            f32x4 z = {b4v, b4v, b4v, b4v};
            z = __builtin_amdgcn_mfma_f32_16x16x32_f16(wf4, h3, z, 0, 0, 0);
            if (q == 0) {                        // younger op #2
                const int e0 = (g << 4) + m;
                if (e0 < E) out[e0] = 1.0f / (1.0f + __expf(-z[0]));
            }
        }
        // label pass-through                    // younger op #3
        const int eL = (g << 4) + lane;
        if (lane < 16 && eL < E) out[E + eL] = (float)ed_cur.w;

        if (last) break;
        // ---- shadow work: offsets for the NEXT refill (depends on ed_fut only)
        calc_off(ed_fut, off_buf);
        g = gn; gn = gf; ed_cur = ed_nxt; ed_nxt = ed_fut;
    }
}

extern "C" void kernel_launch(void* const* d_in, const int* in_sizes, int n_in,
                              void* d_out, int out_size, void* d_ws, size_t ws_size,
                              hipStream_t stream)
{
    const float* drug  = (const float*)d_in[0];
    // d_in[1] (cell_hidden_out), d_in[3] (proj_W), d_in[4] (proj_b): dead code
    const int*   edges = (const int*)d_in[2];
    const float* W1 = (const float*)d_in[5];
    const float* b1 = (const float*)d_in[6];
    const float* W2 = (const float*)d_in[7];
    const float* b2 = (const float*)d_in[8];
    const float* W3 = (const float*)d_in[9];
    const float* b3 = (const float*)d_in[10];
    const float* W4 = (const float*)d_in[11];
    const float* b4 = (const float*)d_in[12];
    float* out = (float*)d_out;
    f16*   tab = (f16*)d_ws;   // [0,1MB): f16 table; [1MB,+13KB): weight blob

    const int E  = in_sizes[2] / 4;
    const int NG = (E + 15) / 16;

    hipLaunchKernelGGL(synergy_prepass, dim3(513), dim3(256), 0, stream,
                       drug, W1, W2, W3, W4, tab);
    int blocks = (NG + 3) / 4;
    if (blocks > 768) blocks = 768;          // 3 blocks/CU x 256 CUs
    hipLaunchKernelGGL(synergy_main, dim3(blocks), dim3(256), 0, stream,
                       tab, edges, b1, b2, b3, b4, out, E, NG);
}